// Round 9
// baseline (5151.620 us; speedup 1.0000x reference)
//
#include <hip/hip_runtime.h>

#define N_NODES 100000
#define N_EDGES 3200000
#define D_IN    512
#define D_OUT   256

// bucket binning params
#define NB        1563            // ceil(100000 / 64) buckets of 64 nodes
#define NBLK_BIN  128
#define T_BIN     ((N_EDGES + NBLK_BIN - 1) / NBLK_BIN)   // 25000

typedef short sh8 __attribute__((ext_vector_type(8)));
typedef float f4  __attribute__((ext_vector_type(4)));

__device__ __forceinline__ unsigned short bf16rn(float f) {
    unsigned u = __float_as_uint(f);
    unsigned r = (u + 0x7FFFu + ((u >> 16) & 1u)) >> 16;
    return (unsigned short)r;
}

__device__ __forceinline__ float bf2f(unsigned short h) {
    return __uint_as_float((unsigned)h << 16);
}

__device__ __forceinline__ void gload_lds16(const void* g, void* l) {
    __builtin_amdgcn_global_load_lds(
        (const __attribute__((address_space(1))) void*)g,
        (__attribute__((address_space(3))) void*)l, 16, 0, 0);
}

// ---------------------------------------------------------------------------
// Pack W[512][256] fp32 -> bf16 hi/lo in MFMA-fragment-major order
// ---------------------------------------------------------------------------
__global__ __launch_bounds__(256) void wpack_kernel(const float* __restrict__ w,
                                                    short* __restrict__ wp) {
    const int id = blockIdx.x * 256 + threadIdx.x;   // 0..16383
    const int l = id & 63;
    const int b = (id >> 6) & 15;
    const int s = id >> 10;
    const int n  = b * 16 + (l & 15);
    const int k0 = s * 32 + (l >> 4) * 8;
    sh8 hi8, lo8;
#pragma unroll
    for (int j = 0; j < 8; ++j) {
        float f = w[(size_t)(k0 + j) * D_OUT + n];
        unsigned short h = bf16rn(f);
        float fh = bf2f(h);
        hi8[j] = (short)h;
        lo8[j] = (short)bf16rn(f - fh);
    }
    short* dst = wp + (size_t)(s * 16 + b) * 1024 + (size_t)l * 8;
    *reinterpret_cast<sh8*>(dst)       = hi8;
    *reinterpret_cast<sh8*>(dst + 512) = lo8;
}

// ---------------------------------------------------------------------------
// GEMM: xw_bf16[N,256] = x[N,512] @ W — split-bf16 MFMA (hi*hi + hi*lo + lo*hi)
// ---------------------------------------------------------------------------
__global__ __launch_bounds__(256) void gemm_mfma(const float* __restrict__ x,
                                                 const short* __restrict__ wp,
                                                 unsigned short* __restrict__ xwh) {
    __shared__ __align__(16) short A_lds[64 * 64];
    __shared__ __align__(16) short B_lds[16384];

    const int tid  = threadIdx.x;
    const int wave = tid >> 6;
    const int lane = tid & 63;
    const int r0   = blockIdx.x * 64;

    f4 acc[4][4];
#pragma unroll
    for (int i = 0; i < 4; ++i)
#pragma unroll
        for (int j = 0; j < 4; ++j) acc[i][j] = (f4){0.f, 0.f, 0.f, 0.f};

    const int sr  = tid >> 2;
    const int skg = tid & 3;
    const int grow = r0 + sr;
    const bool rok = grow < N_NODES;
    const float* xbase = x + (size_t)grow * D_IN + skg * 8;
    const int aw_hi = sr * 128 + ((skg ^ (sr & 7)) << 4);
    const int aw_lo = aw_hi ^ 0x40;
    char* Ac = reinterpret_cast<char*>(A_lds);
    char* Bc = reinterpret_cast<char*>(B_lds);

    const int kg  = lane >> 4;
    const int l7  = lane & 7;
    const int l15 = lane & 15;

    for (int s = 0; s < 16; ++s) {
        const short* bs = wp + (size_t)s * 16384;
#pragma unroll
        for (int rr = 0; rr < 8; ++rr) {
            gload_lds16(bs + rr * 2048 + tid * 8, &B_lds[rr * 2048 + wave * 512]);
        }
        float fv[8] = {0.f, 0.f, 0.f, 0.f, 0.f, 0.f, 0.f, 0.f};
        if (rok) {
            float4 v0 = *reinterpret_cast<const float4*>(xbase + s * 32);
            float4 v1 = *reinterpret_cast<const float4*>(xbase + s * 32 + 4);
            fv[0] = v0.x; fv[1] = v0.y; fv[2] = v0.z; fv[3] = v0.w;
            fv[4] = v1.x; fv[5] = v1.y; fv[6] = v1.z; fv[7] = v1.w;
        }
        sh8 hi8, lo8;
#pragma unroll
        for (int j = 0; j < 8; ++j) {
            unsigned short h = bf16rn(fv[j]);
            float fh = bf2f(h);
            hi8[j] = (short)h;
            lo8[j] = (short)bf16rn(fv[j] - fh);
        }
        *reinterpret_cast<sh8*>(Ac + aw_hi) = hi8;
        *reinterpret_cast<sh8*>(Ac + aw_lo) = lo8;
        __syncthreads();

        sh8 ah[4], al[4], bh[4], bl[4];
#pragma unroll
        for (int mf = 0; mf < 4; ++mf) {
            const int rowb = (mf * 16 + l15) * 128;
            const int ghi  = (kg ^ l7) << 4;
            ah[mf] = *reinterpret_cast<const sh8*>(Ac + rowb + ghi);
            al[mf] = *reinterpret_cast<const sh8*>(Ac + rowb + (ghi ^ 0x40));
        }
#pragma unroll
        for (int nf = 0; nf < 4; ++nf) {
            const int base = (wave * 4 + nf) * 2048 + lane * 16;
            bh[nf] = *reinterpret_cast<const sh8*>(Bc + base);
            bl[nf] = *reinterpret_cast<const sh8*>(Bc + base + 1024);
        }
#pragma unroll
        for (int mf = 0; mf < 4; ++mf)
#pragma unroll
            for (int nf = 0; nf < 4; ++nf) {
                acc[mf][nf] = __builtin_amdgcn_mfma_f32_16x16x32_bf16(ah[mf], bh[nf], acc[mf][nf], 0, 0, 0);
                acc[mf][nf] = __builtin_amdgcn_mfma_f32_16x16x32_bf16(ah[mf], bl[nf], acc[mf][nf], 0, 0, 0);
                acc[mf][nf] = __builtin_amdgcn_mfma_f32_16x16x32_bf16(al[mf], bh[nf], acc[mf][nf], 0, 0, 0);
            }
        __syncthreads();
    }

    const int orow = (lane >> 4) * 4;
    const int ocol = wave * 64 + l15;
#pragma unroll
    for (int mf = 0; mf < 4; ++mf) {
#pragma unroll
        for (int rg = 0; rg < 4; ++rg) {
            const int row = r0 + mf * 16 + orow + rg;
            if (row < N_NODES) {
                unsigned short* dst = xwh + (size_t)row * D_OUT + ocol;
#pragma unroll
                for (int nf = 0; nf < 4; ++nf) dst[nf * 16] = bf16rn(acc[mf][nf][rg]);
            }
        }
    }
}

// ---------------------------------------------------------------------------
// K1: per-block bucket histograms (bHist[blk][b])
// ---------------------------------------------------------------------------
__global__ __launch_bounds__(256) void bucket_count_kernel(const int* __restrict__ erow,
                                                           int* __restrict__ blockHist) {
    __shared__ int h[NB];
    for (int i = threadIdx.x; i < NB; i += 256) h[i] = 0;
    __syncthreads();
    const int start = blockIdx.x * T_BIN;
    const int stop  = min(start + T_BIN, N_EDGES);
    for (int e = start + threadIdx.x; e < stop; e += 256)
        atomicAdd(&h[erow[e] >> 6], 1);
    __syncthreads();
    int* dst = blockHist + (size_t)blockIdx.x * NB;
    for (int i = threadIdx.x; i < NB; i += 256) dst[i] = h[i];
}

// K2a: per-bucket column prefix over the 128 blocks (in place) + totals.
__global__ __launch_bounds__(256) void bscanA_kernel(int* __restrict__ bH,
                                                     int* __restrict__ tot) {
    const int b = blockIdx.x * 256 + threadIdx.x;
    if (b >= NB) return;
    int run = 0;
    for (int blk = 0; blk < NBLK_BIN; ++blk) {
        int* p = bH + (size_t)blk * NB + b;
        const int v = *p;
        *p = run;
        run += v;
    }
    tot[b] = run;
}

// K2b (1 block): exclusive scan over bucket totals -> bptr[0..NB]
__global__ __launch_bounds__(256) void bscanB_kernel(const int* __restrict__ tot,
                                                     int* __restrict__ bptr) {
    __shared__ int lds[256];
    const int tid = threadIdx.x;
    int carry = 0;
    for (int c = 0; c < (NB + 255) / 256; ++c) {
        const int idx = c * 256 + tid;
        const int v = (idx < NB) ? tot[idx] : 0;
        lds[tid] = v;
        __syncthreads();
        for (int off = 1; off < 256; off <<= 1) {
            int t = (tid >= off) ? lds[tid - off] : 0;
            __syncthreads();
            lds[tid] += t;
            __syncthreads();
        }
        const int exc = carry + lds[tid] - v;
        if (idx < NB) bptr[idx] = exc;
        if (idx == NB - 1) bptr[NB] = exc + v;
        carry += lds[255];
        __syncthreads();
    }
}

// K2c: add bucket offsets to every (blk, b) base.  grid = (7, 128)
__global__ __launch_bounds__(256) void bscanC_kernel(int* __restrict__ bH,
                                                     const int* __restrict__ bptr) {
    const int b = blockIdx.x * 256 + threadIdx.x;
    if (b >= NB) return;
    bH[(size_t)blockIdx.y * NB + b] += bptr[b];
}

// K3: binned scatter. tpack = { (lrow<<17)|col , f32 val }, grouped by bucket
__global__ __launch_bounds__(256) void bucket_scatter_kernel(const int* __restrict__ erow,
                                                             const int* __restrict__ ecol,
                                                             const float* __restrict__ eval_,
                                                             const int* __restrict__ base,
                                                             int2* __restrict__ tpack) {
    __shared__ int lcnt[NB];
    for (int i = threadIdx.x; i < NB; i += 256) lcnt[i] = 0;
    __syncthreads();
    const int start = blockIdx.x * T_BIN;
    const int stop  = min(start + T_BIN, N_EDGES);
    const int* bbase = base + (size_t)blockIdx.x * NB;
    for (int e = start + threadIdx.x; e < stop; e += 256) {
        const int r = erow[e];
        const int b = r >> 6;
        const int loc = atomicAdd(&lcnt[b], 1);
        const int p = bbase[b] + loc;
        int2 pk;
        pk.x = ((r & 63) << 17) | ecol[e];
        pk.y = __float_as_int(eval_[e]);
        tpack[p] = pk;
    }
}

// ---------------------------------------------------------------------------
// K4: bucket aggregate — one block (8 waves) per 64-node bucket.
// smem[64][256] fp32 accum (64 KB).  Wave takes one edge: gathers the 512B
// xwh row (4 x coalesced 128B ushort loads, lane covers cols l+64j) and
// LDS-atomic-adds into the edge's row (banks l%32 -> conflict-free).
// Epilogue: bias + relu + coalesced float4 writes.
// ---------------------------------------------------------------------------
__global__ __launch_bounds__(512) void bucket_agg_kernel(const int* __restrict__ bptr,
                                                         const int2* __restrict__ tpack,
                                                         const unsigned short* __restrict__ xwh,
                                                         const float* __restrict__ bias,
                                                         float* __restrict__ out) {
    __shared__ float smem[64 * 256];   // 64 KB
    const int tid = threadIdx.x;
    const int wv  = tid >> 6;
    const int l   = tid & 63;
    const int b   = blockIdx.x;

    float4* s4 = reinterpret_cast<float4*>(smem);
#pragma unroll
    for (int i = 0; i < 8; ++i) s4[tid + i * 512] = (float4){0.f, 0.f, 0.f, 0.f};
    __syncthreads();

    const int beg = bptr[b], end = bptr[b + 1];

    int e = beg + wv;
    for (; e + 8 < end; e += 16) {
        const int2 u0 = tpack[e];
        const int2 u1 = tpack[e + 8];
        const int   c0 = u0.x & 0x1FFFF, r0 = u0.x >> 17;
        const int   c1 = u1.x & 0x1FFFF, r1 = u1.x >> 17;
        const float v0 = __int_as_float(u0.y);
        const float v1 = __int_as_float(u1.y);
        const unsigned short* row0 = xwh + (size_t)c0 * 256 + l;
        const unsigned short* row1 = xwh + (size_t)c1 * 256 + l;
        unsigned short m0[4], m1[4];
#pragma unroll
        for (int j = 0; j < 4; ++j) m0[j] = row0[j * 64];
#pragma unroll
        for (int j = 0; j < 4; ++j) m1[j] = row1[j * 64];
        float* d0 = smem + r0 * 256 + l;
        float* d1 = smem + r1 * 256 + l;
#pragma unroll
        for (int j = 0; j < 4; ++j) atomicAdd(d0 + j * 64, v0 * bf2f(m0[j]));
#pragma unroll
        for (int j = 0; j < 4; ++j) atomicAdd(d1 + j * 64, v1 * bf2f(m1[j]));
    }
    if (e < end) {
        const int2 u = tpack[e];
        const int   c = u.x & 0x1FFFF, r = u.x >> 17;
        const float v = __int_as_float(u.y);
        const unsigned short* row = xwh + (size_t)c * 256 + l;
        unsigned short m[4];
#pragma unroll
        for (int j = 0; j < 4; ++j) m[j] = row[j * 64];
        float* d = smem + r * 256 + l;
#pragma unroll
        for (int j = 0; j < 4; ++j) atomicAdd(d + j * 64, v * bf2f(m[j]));
    }
    __syncthreads();

    // epilogue: 8 threads per row, 32 cols each
    const int row  = tid >> 3;
    const int node = (b << 6) + row;
    if (node < N_NODES) {
        const int c0 = (tid & 7) * 32;
        const float* src = smem + row * 256 + c0;
        float* dst = out + (size_t)node * 256 + c0;
#pragma unroll
        for (int k = 0; k < 8; ++k) {
            float4 a  = *reinterpret_cast<const float4*>(src + k * 4);
            float4 bb = *reinterpret_cast<const float4*>(bias + c0 + k * 4);
            float4 r;
            r.x = fmaxf(a.x + bb.x, 0.f);
            r.y = fmaxf(a.y + bb.y, 0.f);
            r.z = fmaxf(a.z + bb.z, 0.f);
            r.w = fmaxf(a.w + bb.w, 0.f);
            *reinterpret_cast<float4*>(dst + k * 4) = r;
        }
    }
}

// ---------------------------------------------------------------------------
extern "C" void kernel_launch(void* const* d_in, const int* in_sizes, int n_in,
                              void* d_out, int out_size, void* d_ws, size_t ws_size,
                              hipStream_t stream) {
    const float* x     = (const float*)d_in[0];
    const int*   erow  = (const int*)d_in[1];
    const int*   ecol  = (const int*)d_in[2];
    const float* eval_ = (const float*)d_in[3];
    const float* w     = (const float*)d_in[4];
    const float* bias  = (const float*)d_in[5];
    float* out = (float*)d_out;

    char* ws = (char*)d_ws;
    size_t o = 0;
    unsigned short* xwh = (unsigned short*)(ws + o); o += (size_t)N_NODES * D_OUT * 2;  // 51.2 MB
    short* wp      = (short*)(ws + o); o += (size_t)16 * 16384 * 2;                     // 512 KB
    int*   bHist   = (int*)(ws + o);   o += (size_t)NBLK_BIN * NB * 4;                  // 800 KB
    int*   tot     = (int*)(ws + o);   o += (((size_t)NB * 4) + 15) & ~(size_t)15;
    int*   bptr    = (int*)(ws + o);   o += (((size_t)(NB + 1) * 4) + 15) & ~(size_t)15;
    int2*  tpack   = (int2*)(ws + o);  o += (size_t)N_EDGES * 8;                        // 25.6 MB

    // W pack + GEMM
    wpack_kernel<<<64, 256, 0, stream>>>(w, wp);
    gemm_mfma<<<(N_NODES + 63) / 64, 256, 0, stream>>>(x, wp, xwh);

    // bucket binning (2-level scatter, no CSR)
    bucket_count_kernel<<<NBLK_BIN, 256, 0, stream>>>(erow, bHist);
    bscanA_kernel<<<(NB + 255) / 256, 256, 0, stream>>>(bHist, tot);
    bscanB_kernel<<<1, 256, 0, stream>>>(tot, bptr);
    {
        dim3 g((NB + 255) / 256, NBLK_BIN);
        bscanC_kernel<<<g, 256, 0, stream>>>(bHist, bptr);
    }
    bucket_scatter_kernel<<<NBLK_BIN, 256, 0, stream>>>(erow, ecol, eval_, bHist, tpack);

    // bucket aggregate + bias + relu
    bucket_agg_kernel<<<NB, 512, 0, stream>>>(bptr, tpack, xwh, bias, out);
}

// Round 10
// 778.659 us; speedup vs baseline: 6.6160x; 6.6160x over previous
//
#include <hip/hip_runtime.h>

#define N_NODES 100000
#define N_EDGES 3200000
#define D_IN    512
#define D_OUT   256

// bucket binning params
#define NB        1563            // ceil(100000 / 64) buckets of 64 nodes
#define NBLK_BIN  128
#define T_BIN     ((N_EDGES + NBLK_BIN - 1) / NBLK_BIN)   // 25000
#define CH        2048            // agg chunk capacity (16 KB LDS)

typedef short sh8 __attribute__((ext_vector_type(8)));
typedef float f4  __attribute__((ext_vector_type(4)));

__device__ __forceinline__ unsigned short bf16rn(float f) {
    unsigned u = __float_as_uint(f);
    unsigned r = (u + 0x7FFFu + ((u >> 16) & 1u)) >> 16;
    return (unsigned short)r;
}

__device__ __forceinline__ float bf2f(unsigned short h) {
    return __uint_as_float((unsigned)h << 16);
}

__device__ __forceinline__ void gload_lds16(const void* g, void* l) {
    __builtin_amdgcn_global_load_lds(
        (const __attribute__((address_space(1))) void*)g,
        (__attribute__((address_space(3))) void*)l, 16, 0, 0);
}

// ---------------------------------------------------------------------------
// Pack W[512][256] fp32 -> bf16 hi/lo in MFMA-fragment-major order
// ---------------------------------------------------------------------------
__global__ __launch_bounds__(256) void wpack_kernel(const float* __restrict__ w,
                                                    short* __restrict__ wp) {
    const int id = blockIdx.x * 256 + threadIdx.x;   // 0..16383
    const int l = id & 63;
    const int b = (id >> 6) & 15;
    const int s = id >> 10;
    const int n  = b * 16 + (l & 15);
    const int k0 = s * 32 + (l >> 4) * 8;
    sh8 hi8, lo8;
#pragma unroll
    for (int j = 0; j < 8; ++j) {
        float f = w[(size_t)(k0 + j) * D_OUT + n];
        unsigned short h = bf16rn(f);
        float fh = bf2f(h);
        hi8[j] = (short)h;
        lo8[j] = (short)bf16rn(f - fh);
    }
    short* dst = wp + (size_t)(s * 16 + b) * 1024 + (size_t)l * 8;
    *reinterpret_cast<sh8*>(dst)       = hi8;
    *reinterpret_cast<sh8*>(dst + 512) = lo8;
}

// ---------------------------------------------------------------------------
// GEMM: xw_bf16[N,256] = x[N,512] @ W — split-bf16 MFMA (hi*hi + hi*lo + lo*hi)
// ---------------------------------------------------------------------------
__global__ __launch_bounds__(256) void gemm_mfma(const float* __restrict__ x,
                                                 const short* __restrict__ wp,
                                                 unsigned short* __restrict__ xwh) {
    __shared__ __align__(16) short A_lds[64 * 64];
    __shared__ __align__(16) short B_lds[16384];

    const int tid  = threadIdx.x;
    const int wave = tid >> 6;
    const int lane = tid & 63;
    const int r0   = blockIdx.x * 64;

    f4 acc[4][4];
#pragma unroll
    for (int i = 0; i < 4; ++i)
#pragma unroll
        for (int j = 0; j < 4; ++j) acc[i][j] = (f4){0.f, 0.f, 0.f, 0.f};

    const int sr  = tid >> 2;
    const int skg = tid & 3;
    const int grow = r0 + sr;
    const bool rok = grow < N_NODES;
    const float* xbase = x + (size_t)grow * D_IN + skg * 8;
    const int aw_hi = sr * 128 + ((skg ^ (sr & 7)) << 4);
    const int aw_lo = aw_hi ^ 0x40;
    char* Ac = reinterpret_cast<char*>(A_lds);
    char* Bc = reinterpret_cast<char*>(B_lds);

    const int kg  = lane >> 4;
    const int l7  = lane & 7;
    const int l15 = lane & 15;

    for (int s = 0; s < 16; ++s) {
        const short* bs = wp + (size_t)s * 16384;
#pragma unroll
        for (int rr = 0; rr < 8; ++rr) {
            gload_lds16(bs + rr * 2048 + tid * 8, &B_lds[rr * 2048 + wave * 512]);
        }
        float fv[8] = {0.f, 0.f, 0.f, 0.f, 0.f, 0.f, 0.f, 0.f};
        if (rok) {
            float4 v0 = *reinterpret_cast<const float4*>(xbase + s * 32);
            float4 v1 = *reinterpret_cast<const float4*>(xbase + s * 32 + 4);
            fv[0] = v0.x; fv[1] = v0.y; fv[2] = v0.z; fv[3] = v0.w;
            fv[4] = v1.x; fv[5] = v1.y; fv[6] = v1.z; fv[7] = v1.w;
        }
        sh8 hi8, lo8;
#pragma unroll
        for (int j = 0; j < 8; ++j) {
            unsigned short h = bf16rn(fv[j]);
            float fh = bf2f(h);
            hi8[j] = (short)h;
            lo8[j] = (short)bf16rn(fv[j] - fh);
        }
        *reinterpret_cast<sh8*>(Ac + aw_hi) = hi8;
        *reinterpret_cast<sh8*>(Ac + aw_lo) = lo8;
        __syncthreads();

        sh8 ah[4], al[4], bh[4], bl[4];
#pragma unroll
        for (int mf = 0; mf < 4; ++mf) {
            const int rowb = (mf * 16 + l15) * 128;
            const int ghi  = (kg ^ l7) << 4;
            ah[mf] = *reinterpret_cast<const sh8*>(Ac + rowb + ghi);
            al[mf] = *reinterpret_cast<const sh8*>(Ac + rowb + (ghi ^ 0x40));
        }
#pragma unroll
        for (int nf = 0; nf < 4; ++nf) {
            const int base = (wave * 4 + nf) * 2048 + lane * 16;
            bh[nf] = *reinterpret_cast<const sh8*>(Bc + base);
            bl[nf] = *reinterpret_cast<const sh8*>(Bc + base + 1024);
        }
#pragma unroll
        for (int mf = 0; mf < 4; ++mf)
#pragma unroll
            for (int nf = 0; nf < 4; ++nf) {
                acc[mf][nf] = __builtin_amdgcn_mfma_f32_16x16x32_bf16(ah[mf], bh[nf], acc[mf][nf], 0, 0, 0);
                acc[mf][nf] = __builtin_amdgcn_mfma_f32_16x16x32_bf16(ah[mf], bl[nf], acc[mf][nf], 0, 0, 0);
                acc[mf][nf] = __builtin_amdgcn_mfma_f32_16x16x32_bf16(al[mf], bh[nf], acc[mf][nf], 0, 0, 0);
            }
        __syncthreads();
    }

    const int orow = (lane >> 4) * 4;
    const int ocol = wave * 64 + l15;
#pragma unroll
    for (int mf = 0; mf < 4; ++mf) {
#pragma unroll
        for (int rg = 0; rg < 4; ++rg) {
            const int row = r0 + mf * 16 + orow + rg;
            if (row < N_NODES) {
                unsigned short* dst = xwh + (size_t)row * D_OUT + ocol;
#pragma unroll
                for (int nf = 0; nf < 4; ++nf) dst[nf * 16] = bf16rn(acc[mf][nf][rg]);
            }
        }
    }
}

// ---------------------------------------------------------------------------
// K1: per-block bucket histograms (bHist[blk][b])
// ---------------------------------------------------------------------------
__global__ __launch_bounds__(256) void bucket_count_kernel(const int* __restrict__ erow,
                                                           int* __restrict__ blockHist) {
    __shared__ int h[NB];
    for (int i = threadIdx.x; i < NB; i += 256) h[i] = 0;
    __syncthreads();
    const int start = blockIdx.x * T_BIN;
    const int stop  = min(start + T_BIN, N_EDGES);
    for (int e = start + threadIdx.x; e < stop; e += 256)
        atomicAdd(&h[erow[e] >> 6], 1);
    __syncthreads();
    int* dst = blockHist + (size_t)blockIdx.x * NB;
    for (int i = threadIdx.x; i < NB; i += 256) dst[i] = h[i];
}

// K2a: per-bucket column prefix over the 128 blocks (in place) + totals.
__global__ __launch_bounds__(256) void bscanA_kernel(int* __restrict__ bH,
                                                     int* __restrict__ tot) {
    const int b = blockIdx.x * 256 + threadIdx.x;
    if (b >= NB) return;
    int run = 0;
    for (int blk = 0; blk < NBLK_BIN; ++blk) {
        int* p = bH + (size_t)blk * NB + b;
        const int v = *p;
        *p = run;
        run += v;
    }
    tot[b] = run;
}

// K2b (1 block): exclusive scan over bucket totals -> bptr[0..NB]
__global__ __launch_bounds__(256) void bscanB_kernel(const int* __restrict__ tot,
                                                     int* __restrict__ bptr) {
    __shared__ int lds[256];
    const int tid = threadIdx.x;
    int carry = 0;
    for (int c = 0; c < (NB + 255) / 256; ++c) {
        const int idx = c * 256 + tid;
        const int v = (idx < NB) ? tot[idx] : 0;
        lds[tid] = v;
        __syncthreads();
        for (int off = 1; off < 256; off <<= 1) {
            int t = (tid >= off) ? lds[tid - off] : 0;
            __syncthreads();
            lds[tid] += t;
            __syncthreads();
        }
        const int exc = carry + lds[tid] - v;
        if (idx < NB) bptr[idx] = exc;
        if (idx == NB - 1) bptr[NB] = exc + v;
        carry += lds[255];
        __syncthreads();
    }
}

// K2c: add bucket offsets to every (blk, b) base.  grid = (7, 128)
__global__ __launch_bounds__(256) void bscanC_kernel(int* __restrict__ bH,
                                                     const int* __restrict__ bptr) {
    const int b = blockIdx.x * 256 + threadIdx.x;
    if (b >= NB) return;
    bH[(size_t)blockIdx.y * NB + b] += bptr[b];
}

// K3: binned scatter. tpack = { (lrow<<17)|col , f32 val }, grouped by bucket
__global__ __launch_bounds__(256) void bucket_scatter_kernel(const int* __restrict__ erow,
                                                             const int* __restrict__ ecol,
                                                             const float* __restrict__ eval_,
                                                             const int* __restrict__ base,
                                                             int2* __restrict__ tpack) {
    __shared__ int lcnt[NB];
    for (int i = threadIdx.x; i < NB; i += 256) lcnt[i] = 0;
    __syncthreads();
    const int start = blockIdx.x * T_BIN;
    const int stop  = min(start + T_BIN, N_EDGES);
    const int* bbase = base + (size_t)blockIdx.x * NB;
    for (int e = start + threadIdx.x; e < stop; e += 256) {
        const int r = erow[e];
        const int b = r >> 6;
        const int loc = atomicAdd(&lcnt[b], 1);
        const int p = bbase[b] + loc;
        int2 pk;
        pk.x = ((r & 63) << 17) | ecol[e];
        pk.y = __float_as_int(eval_[e]);
        tpack[p] = pk;
    }
}

// ---------------------------------------------------------------------------
// K4: bucket aggregate v2 — one block (8 waves) per 64-node bucket.
// Per <=2048-edge chunk: LDS counting-sort by local row (int atomics only),
// then wave wv processes nodes wv*8..wv*8+7 with the measured-fast pattern:
// wave-per-node, ushort4 gather per lane, 8-deep unroll, fp32 register acc.
// No f32 atomics anywhere.  Epilogue: bias + relu + coalesced float4 store.
// ---------------------------------------------------------------------------
__global__ __launch_bounds__(512) void bucket_agg2_kernel(const int* __restrict__ bptr,
                                                          const int2* __restrict__ tpack,
                                                          const ushort4* __restrict__ xwh4,
                                                          const float* __restrict__ bias,
                                                          float* __restrict__ out) {
    __shared__ int2 sbuf[CH];        // 16 KB sorted (packed,val)
    __shared__ int  hist[64];
    __shared__ int  starts[65];
    __shared__ int  cursor[64];

    const int tid = threadIdx.x;
    const int wv  = tid >> 6;
    const int l   = tid & 63;
    const int b   = blockIdx.x;

    const int beg = bptr[b], end = bptr[b + 1];

    f4 acc[8];
#pragma unroll
    for (int i = 0; i < 8; ++i) acc[i] = (f4){0.f, 0.f, 0.f, 0.f};

    for (int cbeg = beg; cbeg < end; cbeg += CH) {
        const int csz = min(CH, end - cbeg);

        if (tid < 64) hist[tid] = 0;
        __syncthreads();

        // histogram; hold this thread's edges in registers (<=4)
        int2 myu[4];
        int  myn = 0;
#pragma unroll
        for (int k = 0; k < 4; ++k) {
            const int i = tid + k * 512;
            if (i < csz) {
                myu[k] = tpack[cbeg + i];
                atomicAdd(&hist[myu[k].x >> 17], 1);
                myn = k + 1;
            }
        }
        __syncthreads();

        // wave-0 shuffle prefix over 64 bins
        if (wv == 0) {
            const int h = hist[l];
            int s = h;
#pragma unroll
            for (int off = 1; off < 64; off <<= 1) {
                const int t = __shfl_up(s, off, 64);
                if (l >= off) s += t;
            }
            starts[l + 1] = s;
            cursor[l]     = s - h;
            if (l == 0) starts[0] = 0;
        }
        __syncthreads();

        // scatter registers -> sorted LDS
#pragma unroll
        for (int k = 0; k < 4; ++k) {
            if (k < myn) {
                const int p = atomicAdd(&cursor[myu[k].x >> 17], 1);
                sbuf[p] = myu[k];
            }
        }
        __syncthreads();

        // compute: wave wv -> local rows wv*8 .. wv*8+7 (contiguous runs)
#pragma unroll
        for (int nn = 0; nn < 8; ++nn) {
            const int ln = wv * 8 + nn;
            const int s0 = starts[ln], s1 = starts[ln + 1];
            int e = s0;
            for (; e + 8 <= s1; e += 8) {
                int2 p8[8];
#pragma unroll
                for (int j = 0; j < 8; ++j) p8[j] = sbuf[e + j];
                ushort4 m8[8];
#pragma unroll
                for (int j = 0; j < 8; ++j)
                    m8[j] = xwh4[(size_t)(p8[j].x & 0x1FFFF) * 64 + l];
#pragma unroll
                for (int j = 0; j < 8; ++j) {
                    const float v = __int_as_float(p8[j].y);
                    acc[nn].x = fmaf(v, bf2f(m8[j].x), acc[nn].x);
                    acc[nn].y = fmaf(v, bf2f(m8[j].y), acc[nn].y);
                    acc[nn].z = fmaf(v, bf2f(m8[j].z), acc[nn].z);
                    acc[nn].w = fmaf(v, bf2f(m8[j].w), acc[nn].w);
                }
            }
            for (; e < s1; ++e) {
                const int2 p = sbuf[e];
                const float v = __int_as_float(p.y);
                const ushort4 m = xwh4[(size_t)(p.x & 0x1FFFF) * 64 + l];
                acc[nn].x = fmaf(v, bf2f(m.x), acc[nn].x);
                acc[nn].y = fmaf(v, bf2f(m.y), acc[nn].y);
                acc[nn].z = fmaf(v, bf2f(m.z), acc[nn].z);
                acc[nn].w = fmaf(v, bf2f(m.w), acc[nn].w);
            }
        }
        __syncthreads();   // protect hist/sbuf before next chunk
    }

    // epilogue
    const float4 bb = reinterpret_cast<const float4*>(bias)[l];
#pragma unroll
    for (int nn = 0; nn < 8; ++nn) {
        const int node = (b << 6) + wv * 8 + nn;
        if (node < N_NODES) {
            float4 r;
            r.x = fmaxf(acc[nn].x + bb.x, 0.f);
            r.y = fmaxf(acc[nn].y + bb.y, 0.f);
            r.z = fmaxf(acc[nn].z + bb.z, 0.f);
            r.w = fmaxf(acc[nn].w + bb.w, 0.f);
            reinterpret_cast<float4*>(out)[(size_t)node * 64 + l] = r;
        }
    }
}

// ---------------------------------------------------------------------------
extern "C" void kernel_launch(void* const* d_in, const int* in_sizes, int n_in,
                              void* d_out, int out_size, void* d_ws, size_t ws_size,
                              hipStream_t stream) {
    const float* x     = (const float*)d_in[0];
    const int*   erow  = (const int*)d_in[1];
    const int*   ecol  = (const int*)d_in[2];
    const float* eval_ = (const float*)d_in[3];
    const float* w     = (const float*)d_in[4];
    const float* bias  = (const float*)d_in[5];
    float* out = (float*)d_out;

    char* ws = (char*)d_ws;
    size_t o = 0;
    unsigned short* xwh = (unsigned short*)(ws + o); o += (size_t)N_NODES * D_OUT * 2;  // 51.2 MB
    short* wp      = (short*)(ws + o); o += (size_t)16 * 16384 * 2;                     // 512 KB
    int*   bHist   = (int*)(ws + o);   o += (size_t)NBLK_BIN * NB * 4;                  // 800 KB
    int*   tot     = (int*)(ws + o);   o += (((size_t)NB * 4) + 15) & ~(size_t)15;
    int*   bptr    = (int*)(ws + o);   o += (((size_t)(NB + 1) * 4) + 15) & ~(size_t)15;
    int2*  tpack   = (int2*)(ws + o);  o += (size_t)N_EDGES * 8;                        // 25.6 MB

    // W pack + GEMM
    wpack_kernel<<<64, 256, 0, stream>>>(w, wp);
    gemm_mfma<<<(N_NODES + 63) / 64, 256, 0, stream>>>(x, wp, xwh);

    // bucket binning (2-level scatter, no CSR)
    bucket_count_kernel<<<NBLK_BIN, 256, 0, stream>>>(erow, bHist);
    bscanA_kernel<<<(NB + 255) / 256, 256, 0, stream>>>(bHist, tot);
    bscanB_kernel<<<1, 256, 0, stream>>>(tot, bptr);
    {
        dim3 g((NB + 255) / 256, NBLK_BIN);
        bscanC_kernel<<<g, 256, 0, stream>>>(bHist, bptr);
    }
    bucket_scatter_kernel<<<NBLK_BIN, 256, 0, stream>>>(erow, ecol, eval_, bHist, tpack);

    // bucket aggregate + bias + relu (in-LDS counting sort, register acc)
    bucket_agg2_kernel<<<NB, 512, 0, stream>>>(
        bptr, tpack, reinterpret_cast<const ushort4*>(xwh), bias, out);
}

// Round 11
// 769.816 us; speedup vs baseline: 6.6920x; 1.0115x over previous
//
#include <hip/hip_runtime.h>

#define N_NODES 100000
#define N_EDGES 3200000
#define D_IN    512
#define D_OUT   256

// bucket binning params
#define NB        1563            // ceil(100000 / 64) buckets of 64 nodes
#define NBLK_BIN  128
#define T_BIN     ((N_EDGES + NBLK_BIN - 1) / NBLK_BIN)   // 25000
#define CH        2048            // agg chunk capacity (16 KB LDS)

typedef short sh8 __attribute__((ext_vector_type(8)));
typedef float f4  __attribute__((ext_vector_type(4)));

__device__ __forceinline__ unsigned short bf16rn(float f) {
    unsigned u = __float_as_uint(f);
    unsigned r = (u + 0x7FFFu + ((u >> 16) & 1u)) >> 16;
    return (unsigned short)r;
}

__device__ __forceinline__ float bf2f(unsigned short h) {
    return __uint_as_float((unsigned)h << 16);
}

__device__ __forceinline__ void gload_lds16(const void* g, void* l) {
    __builtin_amdgcn_global_load_lds(
        (const __attribute__((address_space(1))) void*)g,
        (__attribute__((address_space(3))) void*)l, 16, 0, 0);
}

// ---------------------------------------------------------------------------
// Pack W[512][256] fp32 -> single bf16 in MFMA-fragment-major order:
// wp elems: ((s*16 + b)*64 + lane)*8 + j
//   where n = b*16 + (lane&15), k = s*32 + (lane>>4)*8 + j
// ---------------------------------------------------------------------------
__global__ __launch_bounds__(256) void wpack_kernel(const float* __restrict__ w,
                                                    short* __restrict__ wp) {
    const int id = blockIdx.x * 256 + threadIdx.x;   // 0..16383
    const int l = id & 63;
    const int b = (id >> 6) & 15;
    const int s = id >> 10;
    const int n  = b * 16 + (l & 15);
    const int k0 = s * 32 + (l >> 4) * 8;
    sh8 hi8;
#pragma unroll
    for (int j = 0; j < 8; ++j) {
        hi8[j] = (short)bf16rn(w[(size_t)(k0 + j) * D_OUT + n]);
    }
    *reinterpret_cast<sh8*>(wp + (size_t)(s * 16 + b) * 512 + (size_t)l * 8) = hi8;
}

// ---------------------------------------------------------------------------
// GEMM: xw_bf16[N,256] = x[N,512] @ W_bf16 — 2-term split (x_hi*W + x_lo*W)
// Block: 256 thr (4 waves), BM=64, BN=256 (wave w -> cols w*64..+63), BK=32
// ---------------------------------------------------------------------------
__global__ __launch_bounds__(256) void gemm_mfma(const float* __restrict__ x,
                                                 const short* __restrict__ wp,
                                                 unsigned short* __restrict__ xwh) {
    __shared__ __align__(16) short A_lds[64 * 64];    // 8 KB: hi/lo sets, XOR-swizzled
    __shared__ __align__(16) short B_lds[8192];       // 16 KB: [nblk][lane][8] linear

    const int tid  = threadIdx.x;
    const int wave = tid >> 6;
    const int lane = tid & 63;
    const int r0   = blockIdx.x * 64;

    f4 acc[4][4];
#pragma unroll
    for (int i = 0; i < 4; ++i)
#pragma unroll
        for (int j = 0; j < 4; ++j) acc[i][j] = (f4){0.f, 0.f, 0.f, 0.f};

    const int sr  = tid >> 2;
    const int skg = tid & 3;
    const int grow = r0 + sr;
    const bool rok = grow < N_NODES;
    const float* xbase = x + (size_t)grow * D_IN + skg * 8;
    const int aw_hi = sr * 128 + ((skg ^ (sr & 7)) << 4);
    const int aw_lo = aw_hi ^ 0x40;
    char* Ac = reinterpret_cast<char*>(A_lds);
    char* Bc = reinterpret_cast<char*>(B_lds);

    const int kg  = lane >> 4;
    const int l7  = lane & 7;
    const int l15 = lane & 15;

    for (int s = 0; s < 16; ++s) {
        // ---- stage B (async, linear LDS): 16 KB in 4 calls ----
        const short* bs = wp + (size_t)s * 8192;
#pragma unroll
        for (int rr = 0; rr < 4; ++rr) {
            gload_lds16(bs + rr * 2048 + tid * 8, &B_lds[rr * 2048 + wave * 512]);
        }
        // ---- stage A: load fp32, split to bf16 hi/lo, swizzled ds_write ----
        float fv[8] = {0.f, 0.f, 0.f, 0.f, 0.f, 0.f, 0.f, 0.f};
        if (rok) {
            float4 v0 = *reinterpret_cast<const float4*>(xbase + s * 32);
            float4 v1 = *reinterpret_cast<const float4*>(xbase + s * 32 + 4);
            fv[0] = v0.x; fv[1] = v0.y; fv[2] = v0.z; fv[3] = v0.w;
            fv[4] = v1.x; fv[5] = v1.y; fv[6] = v1.z; fv[7] = v1.w;
        }
        sh8 hi8, lo8;
#pragma unroll
        for (int j = 0; j < 8; ++j) {
            unsigned short h = bf16rn(fv[j]);
            float fh = bf2f(h);
            hi8[j] = (short)h;
            lo8[j] = (short)bf16rn(fv[j] - fh);
        }
        *reinterpret_cast<sh8*>(Ac + aw_hi) = hi8;
        *reinterpret_cast<sh8*>(Ac + aw_lo) = lo8;
        __syncthreads();

        // ---- fragments ----
        sh8 ah[4], al[4], bh[4];
#pragma unroll
        for (int mf = 0; mf < 4; ++mf) {
            const int rowb = (mf * 16 + l15) * 128;
            const int ghi  = (kg ^ l7) << 4;
            ah[mf] = *reinterpret_cast<const sh8*>(Ac + rowb + ghi);
            al[mf] = *reinterpret_cast<const sh8*>(Ac + rowb + (ghi ^ 0x40));
        }
#pragma unroll
        for (int nf = 0; nf < 4; ++nf) {
            bh[nf] = *reinterpret_cast<const sh8*>(Bc + (wave * 4 + nf) * 1024 + lane * 16);
        }
        // ---- MFMA: 32 per K-step ----
#pragma unroll
        for (int mf = 0; mf < 4; ++mf)
#pragma unroll
            for (int nf = 0; nf < 4; ++nf) {
                acc[mf][nf] = __builtin_amdgcn_mfma_f32_16x16x32_bf16(ah[mf], bh[nf], acc[mf][nf], 0, 0, 0);
                acc[mf][nf] = __builtin_amdgcn_mfma_f32_16x16x32_bf16(al[mf], bh[nf], acc[mf][nf], 0, 0, 0);
            }
        __syncthreads();
    }

    const int orow = (lane >> 4) * 4;
    const int ocol = wave * 64 + l15;
#pragma unroll
    for (int mf = 0; mf < 4; ++mf) {
#pragma unroll
        for (int rg = 0; rg < 4; ++rg) {
            const int row = r0 + mf * 16 + orow + rg;
            if (row < N_NODES) {
                unsigned short* dst = xwh + (size_t)row * D_OUT + ocol;
#pragma unroll
                for (int nf = 0; nf < 4; ++nf) dst[nf * 16] = bf16rn(acc[mf][nf][rg]);
            }
        }
    }
}

// ---------------------------------------------------------------------------
// K1: per-block bucket histograms (bHist[blk][b])
// ---------------------------------------------------------------------------
__global__ __launch_bounds__(256) void bucket_count_kernel(const int* __restrict__ erow,
                                                           int* __restrict__ blockHist) {
    __shared__ int h[NB];
    for (int i = threadIdx.x; i < NB; i += 256) h[i] = 0;
    __syncthreads();
    const int start = blockIdx.x * T_BIN;
    const int stop  = min(start + T_BIN, N_EDGES);
    for (int e = start + threadIdx.x; e < stop; e += 256)
        atomicAdd(&h[erow[e] >> 6], 1);
    __syncthreads();
    int* dst = blockHist + (size_t)blockIdx.x * NB;
    for (int i = threadIdx.x; i < NB; i += 256) dst[i] = h[i];
}

// K2a: per-bucket column prefix over the 128 blocks (in place) + totals.
__global__ __launch_bounds__(256) void bscanA_kernel(int* __restrict__ bH,
                                                     int* __restrict__ tot) {
    const int b = blockIdx.x * 256 + threadIdx.x;
    if (b >= NB) return;
    int run = 0;
    for (int blk = 0; blk < NBLK_BIN; ++blk) {
        int* p = bH + (size_t)blk * NB + b;
        const int v = *p;
        *p = run;
        run += v;
    }
    tot[b] = run;
}

// K2b (1 block): exclusive scan over bucket totals -> bptr[0..NB]
__global__ __launch_bounds__(256) void bscanB_kernel(const int* __restrict__ tot,
                                                     int* __restrict__ bptr) {
    __shared__ int lds[256];
    const int tid = threadIdx.x;
    int carry = 0;
    for (int c = 0; c < (NB + 255) / 256; ++c) {
        const int idx = c * 256 + tid;
        const int v = (idx < NB) ? tot[idx] : 0;
        lds[tid] = v;
        __syncthreads();
        for (int off = 1; off < 256; off <<= 1) {
            int t = (tid >= off) ? lds[tid - off] : 0;
            __syncthreads();
            lds[tid] += t;
            __syncthreads();
        }
        const int exc = carry + lds[tid] - v;
        if (idx < NB) bptr[idx] = exc;
        if (idx == NB - 1) bptr[NB] = exc + v;
        carry += lds[255];
        __syncthreads();
    }
}

// K2c: add bucket offsets to every (blk, b) base.  grid = (7, 128)
__global__ __launch_bounds__(256) void bscanC_kernel(int* __restrict__ bH,
                                                     const int* __restrict__ bptr) {
    const int b = blockIdx.x * 256 + threadIdx.x;
    if (b >= NB) return;
    bH[(size_t)blockIdx.y * NB + b] += bptr[b];
}

// K3: binned scatter. tpack = { (lrow<<17)|col , f32 val }, grouped by bucket
__global__ __launch_bounds__(256) void bucket_scatter_kernel(const int* __restrict__ erow,
                                                             const int* __restrict__ ecol,
                                                             const float* __restrict__ eval_,
                                                             const int* __restrict__ base,
                                                             int2* __restrict__ tpack) {
    __shared__ int lcnt[NB];
    for (int i = threadIdx.x; i < NB; i += 256) lcnt[i] = 0;
    __syncthreads();
    const int start = blockIdx.x * T_BIN;
    const int stop  = min(start + T_BIN, N_EDGES);
    const int* bbase = base + (size_t)blockIdx.x * NB;
    for (int e = start + threadIdx.x; e < stop; e += 256) {
        const int r = erow[e];
        const int b = r >> 6;
        const int loc = atomicAdd(&lcnt[b], 1);
        const int p = bbase[b] + loc;
        int2 pk;
        pk.x = ((r & 63) << 17) | ecol[e];
        pk.y = __float_as_int(eval_[e]);
        tpack[p] = pk;
    }
}

// ---------------------------------------------------------------------------
// K4: bucket aggregate v2 — one block (8 waves) per 64-node bucket.
// Per <=2048-edge chunk: LDS counting-sort by local row (int atomics only),
// then wave wv processes nodes wv*8..wv*8+7: wave-per-node, ushort4 gather,
// 8-deep unroll, fp32 register acc.  No f32 atomics anywhere.
// ---------------------------------------------------------------------------
__global__ __launch_bounds__(512) void bucket_agg2_kernel(const int* __restrict__ bptr,
                                                          const int2* __restrict__ tpack,
                                                          const ushort4* __restrict__ xwh4,
                                                          const float* __restrict__ bias,
                                                          float* __restrict__ out) {
    __shared__ int2 sbuf[CH];        // 16 KB sorted (packed,val)
    __shared__ int  hist[64];
    __shared__ int  starts[65];
    __shared__ int  cursor[64];

    const int tid = threadIdx.x;
    const int wv  = tid >> 6;
    const int l   = tid & 63;
    const int b   = blockIdx.x;

    const int beg = bptr[b], end = bptr[b + 1];

    f4 acc[8];
#pragma unroll
    for (int i = 0; i < 8; ++i) acc[i] = (f4){0.f, 0.f, 0.f, 0.f};

    for (int cbeg = beg; cbeg < end; cbeg += CH) {
        const int csz = min(CH, end - cbeg);

        if (tid < 64) hist[tid] = 0;
        __syncthreads();

        // histogram; hold this thread's edges in registers (<=4)
        int2 myu[4];
        int  myn = 0;
#pragma unroll
        for (int k = 0; k < 4; ++k) {
            const int i = tid + k * 512;
            if (i < csz) {
                myu[k] = tpack[cbeg + i];
                atomicAdd(&hist[myu[k].x >> 17], 1);
                myn = k + 1;
            }
        }
        __syncthreads();

        // wave-0 shuffle prefix over 64 bins
        if (wv == 0) {
            const int h = hist[l];
            int s = h;
#pragma unroll
            for (int off = 1; off < 64; off <<= 1) {
                const int t = __shfl_up(s, off, 64);
                if (l >= off) s += t;
            }
            starts[l + 1] = s;
            cursor[l]     = s - h;
            if (l == 0) starts[0] = 0;
        }
        __syncthreads();

        // scatter registers -> sorted LDS
#pragma unroll
        for (int k = 0; k < 4; ++k) {
            if (k < myn) {
                const int p = atomicAdd(&cursor[myu[k].x >> 17], 1);
                sbuf[p] = myu[k];
            }
        }
        __syncthreads();

        // compute: wave wv -> local rows wv*8 .. wv*8+7 (contiguous runs)
#pragma unroll
        for (int nn = 0; nn < 8; ++nn) {
            const int ln = wv * 8 + nn;
            const int s0 = starts[ln], s1 = starts[ln + 1];
            int e = s0;
            for (; e + 8 <= s1; e += 8) {
                int2 p8[8];
#pragma unroll
                for (int j = 0; j < 8; ++j) p8[j] = sbuf[e + j];
                ushort4 m8[8];
#pragma unroll
                for (int j = 0; j < 8; ++j)
                    m8[j] = xwh4[(size_t)(p8[j].x & 0x1FFFF) * 64 + l];
#pragma unroll
                for (int j = 0; j < 8; ++j) {
                    const float v = __int_as_float(p8[j].y);
                    acc[nn].x = fmaf(v, bf2f(m8[j].x), acc[nn].x);
                    acc[nn].y = fmaf(v, bf2f(m8[j].y), acc[nn].y);
                    acc[nn].z = fmaf(v, bf2f(m8[j].z), acc[nn].z);
                    acc[nn].w = fmaf(v, bf2f(m8[j].w), acc[nn].w);
                }
            }
            for (; e < s1; ++e) {
                const int2 p = sbuf[e];
                const float v = __int_as_float(p.y);
                const ushort4 m = xwh4[(size_t)(p.x & 0x1FFFF) * 64 + l];
                acc[nn].x = fmaf(v, bf2f(m.x), acc[nn].x);
                acc[nn].y = fmaf(v, bf2f(m.y), acc[nn].y);
                acc[nn].z = fmaf(v, bf2f(m.z), acc[nn].z);
                acc[nn].w = fmaf(v, bf2f(m.w), acc[nn].w);
            }
        }
        __syncthreads();   // protect hist/sbuf before next chunk
    }

    // epilogue
    const float4 bb = reinterpret_cast<const float4*>(bias)[l];
#pragma unroll
    for (int nn = 0; nn < 8; ++nn) {
        const int node = (b << 6) + wv * 8 + nn;
        if (node < N_NODES) {
            float4 r;
            r.x = fmaxf(acc[nn].x + bb.x, 0.f);
            r.y = fmaxf(acc[nn].y + bb.y, 0.f);
            r.z = fmaxf(acc[nn].z + bb.z, 0.f);
            r.w = fmaxf(acc[nn].w + bb.w, 0.f);
            reinterpret_cast<float4*>(out)[(size_t)node * 64 + l] = r;
        }
    }
}

// ---------------------------------------------------------------------------
extern "C" void kernel_launch(void* const* d_in, const int* in_sizes, int n_in,
                              void* d_out, int out_size, void* d_ws, size_t ws_size,
                              hipStream_t stream) {
    const float* x     = (const float*)d_in[0];
    const int*   erow  = (const int*)d_in[1];
    const int*   ecol  = (const int*)d_in[2];
    const float* eval_ = (const float*)d_in[3];
    const float* w     = (const float*)d_in[4];
    const float* bias  = (const float*)d_in[5];
    float* out = (float*)d_out;

    char* ws = (char*)d_ws;
    size_t o = 0;
    unsigned short* xwh = (unsigned short*)(ws + o); o += (size_t)N_NODES * D_OUT * 2;  // 51.2 MB
    short* wp      = (short*)(ws + o); o += (size_t)16 * 8192 * 2;                      // 256 KB
    int*   bHist   = (int*)(ws + o);   o += (size_t)NBLK_BIN * NB * 4;                  // 800 KB
    int*   tot     = (int*)(ws + o);   o += (((size_t)NB * 4) + 15) & ~(size_t)15;
    int*   bptr    = (int*)(ws + o);   o += (((size_t)(NB + 1) * 4) + 15) & ~(size_t)15;
    int2*  tpack   = (int2*)(ws + o);  o += (size_t)N_EDGES * 8;                        // 25.6 MB

    // W pack + GEMM
    wpack_kernel<<<64, 256, 0, stream>>>(w, wp);
    gemm_mfma<<<(N_NODES + 63) / 64, 256, 0, stream>>>(x, wp, xwh);

    // bucket binning (2-level scatter, no CSR)
    bucket_count_kernel<<<NBLK_BIN, 256, 0, stream>>>(erow, bHist);
    bscanA_kernel<<<(NB + 255) / 256, 256, 0, stream>>>(bHist, tot);
    bscanB_kernel<<<1, 256, 0, stream>>>(tot, bptr);
    {
        dim3 g((NB + 255) / 256, NBLK_BIN);
        bscanC_kernel<<<g, 256, 0, stream>>>(bHist, bptr);
    }
    bucket_scatter_kernel<<<NBLK_BIN, 256, 0, stream>>>(erow, ecol, eval_, bHist, tpack);

    // bucket aggregate + bias + relu (in-LDS counting sort, register acc)
    bucket_agg2_kernel<<<NB, 512, 0, stream>>>(
        bptr, tpack, reinterpret_cast<const ushort4*>(xwh), bias, out);
}